// Round 5
// baseline (222.873 us; speedup 1.0000x reference)
//
#include <hip/hip_runtime.h>
#include <hip/hip_bf16.h>

#define BATCH  4096
#define UNITS  1024
#define CDIM   2048   // K = UNITS + IN_DIM
#define NDIM   4096   // 4 * UNITS (f, i, c, o)

typedef __attribute__((ext_vector_type(8))) short bf16x8;
typedef __attribute__((ext_vector_type(4))) short bf16x4;
typedef __attribute__((ext_vector_type(4))) float f32x4;

__device__ __forceinline__ void gload_lds16(const void* g, void* l) {
    __builtin_amdgcn_global_load_lds(
        (const __attribute__((address_space(1))) unsigned int*)g,
        (__attribute__((address_space(3))) unsigned int*)l, 16, 0, 0);
}

__device__ __forceinline__ float sigm(float x) { return 1.f / (1.f + __expf(-x)); }
__device__ __forceinline__ float tanh_fast(float x) { return 2.f / (1.f + __expf(-2.f * x)) - 1.f; }

__device__ __forceinline__ short f2bf(float f) {
    __hip_bfloat16 h = __float2bfloat16(f);
    return *reinterpret_cast<short*>(&h);
}

// ---- prep v3 (FROZEN control: ~30 us, near 128 MB roofline) -----------------
// Wt row layout (gate-interleaved, 128-periodic):
//   n(u,g) = (u>>5)*128 + ((u>>4)&1)*64 + g*16 + (u&15)
__global__ __launch_bounds__(256) void prep(
        const float* __restrict__ h, const float* __restrict__ in,
        const float* __restrict__ Wf, const float* __restrict__ Wi,
        const float* __restrict__ Wc, const float* __restrict__ Wo,
        __hip_bfloat16* __restrict__ x, __hip_bfloat16* __restrict__ Wt) {
    __shared__ float lds[64 * 65];
    int b = blockIdx.x, tid = threadIdx.x;
    if (b < 4096) {
        int t   = b * 256 + tid;
        int row = t >> 8;
        int c8  = (t & 255) << 3;
        const float* src = (c8 < UNITS) ? (h + (size_t)row * UNITS + c8)
                                        : (in + (size_t)row * UNITS + (c8 - UNITS));
        float4 v0 = ((const float4*)src)[0];
        float4 v1 = ((const float4*)src)[1];
        bf16x8 o;
        o[0] = f2bf(v0.x); o[1] = f2bf(v0.y); o[2] = f2bf(v0.z); o[3] = f2bf(v0.w);
        o[4] = f2bf(v1.x); o[5] = f2bf(v1.y); o[6] = f2bf(v1.z); o[7] = f2bf(v1.w);
        *(bf16x8*)(x + (size_t)row * CDIM + c8) = o;
    } else {
        int idx = b - 4096;               // 2048 blocks = g(4) x kt(32) x ut(16)
        int g = idx >> 9, kt = (idx >> 4) & 31, ut = idx & 15;
        const float* W = (g == 0) ? Wf : (g == 1) ? Wi : (g == 2) ? Wc : Wo;
        int k0 = kt * 64, u0 = ut * 64;
        int r16 = tid & 15, hi = tid >> 4;
#pragma unroll
        for (int it = 0; it < 4; ++it) {
            int kl = it * 16 + hi;
            float4 v = *(const float4*)&W[(size_t)(k0 + kl) * UNITS + u0 + r16 * 4];
            float* d = &lds[kl * 65 + r16 * 4];
            d[0] = v.x; d[1] = v.y; d[2] = v.z; d[3] = v.w;
        }
        __syncthreads();
#pragma unroll
        for (int it = 0; it < 4; ++it) {
            int ul = it * 16 + hi;
            int u  = u0 + ul;
            int n  = ((u >> 5) << 7) + (((u >> 4) & 1) << 6) + (g << 4) + (u & 15);
            bf16x4 o;
#pragma unroll
            for (int j = 0; j < 4; ++j) o[j] = f2bf(lds[(r16 * 4 + j) * 65 + ul]);
            *(bf16x4*)(Wt + (size_t)n * CDIM + k0 + r16 * 4) = o;
        }
    }
}

// ---- gemm v3: hybrid pipeline ----------------------------------------------
// Block 128m x 256n, 4 waves; wave = 128m x 64n (8i x 4j MFMA), BK=64.
// A: LDS via global_load_lds, THREE distinct static buffers (As0/1/2) with
//    compile-time indices (unrolled triples) so alias analysis can keep
//    in-flight gload_lds (to As[nxt2]) from forcing vmcnt(0) before the
//    ds_reads of As[cur]. R0-proven 128B-row layout + chunk^(row&7) swizzle
//    (0 bank conflicts measured).
// B: streamed L2 -> VGPR, 1-deep prefetch (bcur/bnxt). Zero LDS cost: LDS
//    traffic/CU/step = 160 KB (~1880 cyc) < MFMA floor (2484 cyc).
// Waits: issue order per iter = B(t+1) then A(t+2). Compiler's counted wait
// before the bcur=bnxt moves (after the 64-MFMA cluster) drains exactly
// [A(t+1), B(t+1)], leaving A(t+2) in flight across the raw s_barrier.
// Explicit asm vmcnt(4) at iter top is a cheap safety net (first iter: real).
__global__ __launch_bounds__(256, 2) void gemm_lstm(
    const __hip_bfloat16* __restrict__ A,    // [BATCH, CDIM] bf16
    const __hip_bfloat16* __restrict__ Bt,   // [NDIM, CDIM] bf16, gate-interleaved
    const float* __restrict__ b_f, const float* __restrict__ b_i,
    const float* __restrict__ b_c, const float* __restrict__ b_o,
    const float* __restrict__ cell,          // [BATCH, UNITS]
    float* __restrict__ out)                 // [2, BATCH, UNITS]: hidden, cell
{
    __shared__ alignas(16) short As0[128 * 64];   // 3 x 16 KB, distinct objects
    __shared__ alignas(16) short As1[128 * 64];
    __shared__ alignas(16) short As2[128 * 64];
    const int K = CDIM;                      // NT = 32 K-steps of BK=64

    int bid = blockIdx.x;
    int nb  = (bid & 7) * 2 + ((bid >> 3) & 1);
    int mb  = bid >> 4;
    int m0  = mb * 128, n0 = nb * 256;

    int tid  = threadIdx.x;
    int w    = tid >> 6, lane = tid & 63;
    int quad = lane >> 4, r16 = lane & 15;
    int wn   = w * 64;

    f32x4 acc[8][4];
#pragma unroll
    for (int i = 0; i < 8; ++i)
#pragma unroll
        for (int j = 0; j < 4; ++j) acc[i][j] = (f32x4){0.f, 0.f, 0.f, 0.f};

    const short* Ag = (const short*)A  + (size_t)m0 * K;
    const short* Bg = (const short*)Bt + (size_t)(n0 + wn + r16) * K + quad * 8;

    bf16x8 bcur[8], bnxt[8];

#define STAGEA(DST, KT)                                                        \
    { int k0_ = (KT) * 64;                                                     \
      _Pragma("unroll")                                                        \
      for (int q = 0; q < 4; ++q) {                                            \
          int s_ = q * 256 + tid, row_ = s_ >> 3, cg_ = (s_ & 7) ^ (row_ & 7); \
          gload_lds16(Ag + (size_t)row_ * K + k0_ + cg_ * 8,                   \
                      DST + (q * 256 + w * 64) * 8);                           \
      } }

#define KSTEP(T, CUR, NXT2, DOB, DOS, WN)                                      \
    {                                                                          \
        asm volatile("s_waitcnt vmcnt(" #WN ")" ::: "memory");                 \
        __builtin_amdgcn_s_barrier();                                          \
        if (DOB) {                                                             \
            int kb_ = ((T) + 1) * 64;                                          \
            _Pragma("unroll")                                                  \
            for (int ks = 0; ks < 2; ++ks)                                     \
                _Pragma("unroll")                                              \
                for (int j = 0; j < 4; ++j)                                    \
                    bnxt[ks * 4 + j] =                                         \
                        *(const bf16x8*)&Bg[(size_t)(j * 16) * K + kb_ + ks * 32]; \
        }                                                                      \
        if (DOS) STAGEA(NXT2, (T) + 2);                                        \
        _Pragma("unroll")                                                      \
        for (int ks = 0; ks < 2; ++ks) {                                       \
            bf16x8 af[8];                                                      \
            int kc_ = ((quad + ks * 4) ^ (r16 & 7)) * 8;                       \
            _Pragma("unroll")                                                  \
            for (int i = 0; i < 8; ++i)                                        \
                af[i] = *(const bf16x8*)&CUR[(i * 16 + r16) * 64 + kc_];       \
            __builtin_amdgcn_s_setprio(1);                                     \
            _Pragma("unroll")                                                  \
            for (int i = 0; i < 8; ++i)                                        \
                _Pragma("unroll")                                              \
                for (int j = 0; j < 4; ++j)                                    \
                    acc[i][j] = __builtin_amdgcn_mfma_f32_16x16x32_bf16(       \
                        af[i], bcur[ks * 4 + j], acc[i][j], 0, 0, 0);          \
            __builtin_amdgcn_s_setprio(0);                                     \
        }                                                                      \
        if (DOB) {                                                             \
            _Pragma("unroll")                                                  \
            for (int tt = 0; tt < 8; ++tt) bcur[tt] = bnxt[tt];                \
        }                                                                      \
    }

    // Prologue: queue (oldest->newest) = [A(0):4, B(0):8, A(1):4]
    STAGEA(As0, 0);
#pragma unroll
    for (int ks = 0; ks < 2; ++ks)
#pragma unroll
        for (int j = 0; j < 4; ++j)
            bcur[ks * 4 + j] = *(const bf16x8*)&Bg[(size_t)(j * 16) * K + ks * 32];
    STAGEA(As1, 1);

    // 30 steps in unrolled triples (static buffer roles), then 2 tail steps
    for (int t0 = 0; t0 < 30; t0 += 3) {
        KSTEP(t0,     As0, As2, true, true, 4)
        KSTEP(t0 + 1, As1, As0, true, true, 4)
        KSTEP(t0 + 2, As2, As1, true, true, 4)
    }
    KSTEP(30, As0, As2, true,  false, 4)
    KSTEP(31, As1, As0, false, false, 0)

#undef KSTEP
#undef STAGEA

    // ---- fused LSTM epilogue: j = gate, u = nb*64 + (w>>1)*32 + (w&1)*16 + r16
    // C/D layout: col=lane&15, row=quad*4+reg (m89-verified)
    int u = nb * 64 + (w >> 1) * 32 + (w & 1) * 16 + r16;
    float bfv = b_f[u], biv = b_i[u], bcv = b_c[u], bov = b_o[u];
    float* out_h = out;
    float* out_c = out + (size_t)BATCH * UNITS;
#pragma unroll
    for (int i = 0; i < 8; ++i) {
#pragma unroll
        for (int rr = 0; rr < 4; ++rr) {
            int m = m0 + i * 16 + quad * 4 + rr;
            float fg = sigm(acc[i][0][rr] + bfv);
            float ig = sigm(acc[i][1][rr] + biv);
            float cc = tanh_fast(acc[i][2][rr] + bcv);
            float og = sigm(acc[i][3][rr] + bov);
            float cold = cell[(size_t)m * UNITS + u];
            float cn = fg * cold + ig * cc;
            out_h[(size_t)m * UNITS + u] = og * tanh_fast(cn);
            out_c[(size_t)m * UNITS + u] = cn;
        }
    }
}

extern "C" void kernel_launch(void* const* d_in, const int* in_sizes, int n_in,
                              void* d_out, int out_size, void* d_ws, size_t ws_size,
                              hipStream_t stream) {
    const float* inputs = (const float*)d_in[0];
    const float* hidden = (const float*)d_in[1];
    const float* cell   = (const float*)d_in[2];
    const float* Wf = (const float*)d_in[3];
    const float* bf_ = (const float*)d_in[4];
    const float* Wi = (const float*)d_in[5];
    const float* bi_ = (const float*)d_in[6];
    const float* Wc = (const float*)d_in[7];
    const float* bc_ = (const float*)d_in[8];
    const float* Wo = (const float*)d_in[9];
    const float* bo_ = (const float*)d_in[10];
    float* out = (float*)d_out;

    char* ws = (char*)d_ws;
    __hip_bfloat16* x  = (__hip_bfloat16*)ws;                  // 16 MB
    __hip_bfloat16* Wt = (__hip_bfloat16*)(ws + (16u << 20));  // 16 MB

    prep<<<dim3(6144), dim3(256), 0, stream>>>(hidden, inputs, Wf, Wi, Wc, Wo, x, Wt);
    gemm_lstm<<<dim3(512), dim3(256), 0, stream>>>(
        x, Wt, bf_, bi_, bc_, bo_, cell, out);
}

// Round 6
// 198.124 us; speedup vs baseline: 1.1249x; 1.1249x over previous
//
#include <hip/hip_runtime.h>
#include <hip/hip_bf16.h>

#define BATCH  4096
#define UNITS  1024
#define CDIM   2048   // K = UNITS + IN_DIM
#define NDIM   4096   // 4 * UNITS (f, i, c, o)

typedef __attribute__((ext_vector_type(8))) short bf16x8;
typedef __attribute__((ext_vector_type(4))) short bf16x4;
typedef __attribute__((ext_vector_type(4))) float f32x4;

__device__ __forceinline__ void gload_lds16(const void* g, void* l) {
    __builtin_amdgcn_global_load_lds(
        (const __attribute__((address_space(1))) unsigned int*)g,
        (__attribute__((address_space(3))) unsigned int*)l, 16, 0, 0);
}

__device__ __forceinline__ float sigm(float x) { return 1.f / (1.f + __expf(-x)); }
__device__ __forceinline__ float tanh_fast(float x) { return 2.f / (1.f + __expf(-2.f * x)) - 1.f; }

__device__ __forceinline__ short f2bf(float f) {
    __hip_bfloat16 h = __float2bfloat16(f);
    return *reinterpret_cast<short*>(&h);
}

// ---- prep v3 (FROZEN control: ~30 us, near 128 MB roofline) -----------------
// Wt row layout (gate-interleaved, 128-periodic):
//   n(u,g) = (u>>5)*128 + ((u>>4)&1)*64 + g*16 + (u&15)
__global__ __launch_bounds__(256) void prep(
        const float* __restrict__ h, const float* __restrict__ in,
        const float* __restrict__ Wf, const float* __restrict__ Wi,
        const float* __restrict__ Wc, const float* __restrict__ Wo,
        __hip_bfloat16* __restrict__ x, __hip_bfloat16* __restrict__ Wt) {
    __shared__ float lds[64 * 65];
    int b = blockIdx.x, tid = threadIdx.x;
    if (b < 4096) {
        int t   = b * 256 + tid;
        int row = t >> 8;
        int c8  = (t & 255) << 3;
        const float* src = (c8 < UNITS) ? (h + (size_t)row * UNITS + c8)
                                        : (in + (size_t)row * UNITS + (c8 - UNITS));
        float4 v0 = ((const float4*)src)[0];
        float4 v1 = ((const float4*)src)[1];
        bf16x8 o;
        o[0] = f2bf(v0.x); o[1] = f2bf(v0.y); o[2] = f2bf(v0.z); o[3] = f2bf(v0.w);
        o[4] = f2bf(v1.x); o[5] = f2bf(v1.y); o[6] = f2bf(v1.z); o[7] = f2bf(v1.w);
        *(bf16x8*)(x + (size_t)row * CDIM + c8) = o;
    } else {
        int idx = b - 4096;               // 2048 blocks = g(4) x kt(32) x ut(16)
        int g = idx >> 9, kt = (idx >> 4) & 31, ut = idx & 15;
        const float* W = (g == 0) ? Wf : (g == 1) ? Wi : (g == 2) ? Wc : Wo;
        int k0 = kt * 64, u0 = ut * 64;
        int r16 = tid & 15, hi = tid >> 4;
#pragma unroll
        for (int it = 0; it < 4; ++it) {
            int kl = it * 16 + hi;
            float4 v = *(const float4*)&W[(size_t)(k0 + kl) * UNITS + u0 + r16 * 4];
            float* d = &lds[kl * 65 + r16 * 4];
            d[0] = v.x; d[1] = v.y; d[2] = v.z; d[3] = v.w;
        }
        __syncthreads();
#pragma unroll
        for (int it = 0; it < 4; ++it) {
            int ul = it * 16 + hi;
            int u  = u0 + ul;
            int n  = ((u >> 5) << 7) + (((u >> 4) & 1) << 6) + (g << 4) + (u & 15);
            bf16x4 o;
#pragma unroll
            for (int j = 0; j < 4; ++j) o[j] = f2bf(lds[(r16 * 4 + j) * 65 + ul]);
            *(bf16x4*)(Wt + (size_t)n * CDIM + k0 + r16 * 4) = o;
        }
    }
}

// ---- gemm v4: 256x256 8-phase template (m201-derived, plain HIP) ------------
// 512 thr = 8 waves (2M x 4N); wave out = 128m x 64n (acc[8][4]); BK=64.
// LDS 128 KB dynamic: A[p][h], B[p][h] half-tiles of 128x64 bf16 (16 KB each),
// p = K-tile dbuf (tile t -> p = t&1), h = row-half. Proven xor8 chunk
// swizzle (stage cg=(s&7)^(row&7); read kc=((quad+ks*4)^(r16&7))*8 — 0
// conflicts measured in R0: consecutive 8 lanes hit all 8 chunks).
// Iteration u computes tiles 2u (p0: P1-P4) and 2u+1 (p1: P5-P8); each phase
// = quadrant (ks, ih): ds_read 4 A-frags (+4 B-frags when ih==0, reused at
// ih==1), stage ONE half-tile (2 gload_lds/thread), s_barrier, 16 MFMA
// (setprio 1), s_barrier. Raw asm barriers w/ "memory": no compiler vmcnt(0)
// drain; LDS ops cannot cross phase boundaries.
// Stage slots (issue only after target's last reader barrier):
//   P1: A[p1,h0](2u+1)  P2: A[p1,h1](2u+1)  P3: B[p1,h1](2u+1)   [p1 A last
//   read P8 prev, B last read P7 prev]
//   P4: B[p0,h0](2u+2)  P5: B[p0,h1](2u+2)  [p0 B last ds_read P3]
//   P6: A[p0,h0](2u+2)  P7: A[p0,h1](2u+2)  [p0 A last ds_read P4]
//   P8: B[p1,h0](2u+3)  [p1 B last read P7]
// Counted waits (uniform issue order across waves -> collective after barrier):
//   end-P4: queue [B(p1,h0)@P8prev, P1, P2, P3, P4] -> vmcnt(2) retires
//           through P3 = buf p1 (tile 2u+1) complete before P5 reads.
//   end-P8: queue [P4..P8] -> vmcnt(2) retires P4..P7 = buf p0 (tile 2u+2)
//           complete before next P1 reads.
__global__ __launch_bounds__(512, 2) void gemm_lstm(
    const __hip_bfloat16* __restrict__ A,    // [BATCH, CDIM] bf16
    const __hip_bfloat16* __restrict__ Bt,   // [NDIM, CDIM] bf16, gate-interleaved
    const float* __restrict__ b_f, const float* __restrict__ b_i,
    const float* __restrict__ b_c, const float* __restrict__ b_o,
    const float* __restrict__ cell,          // [BATCH, UNITS]
    float* __restrict__ out)                 // [2, BATCH, UNITS]: hidden, cell
{
    extern __shared__ short smem[];          // 65536 shorts = 128 KB
    const int K = CDIM;

    // XCD swizzle: 256 blocks, xcd = bid&7 -> contiguous 2-nb slice (L2-resident)
    int bid = blockIdx.x;
    int nb  = (bid & 7) * 2 + ((bid >> 3) & 1);   // 0..15
    int mb  = bid >> 4;                           // 0..15
    int m0  = mb * 256, n0 = nb * 256;

    int tid  = threadIdx.x;
    int w    = tid >> 6, lane = tid & 63;
    int wm   = w >> 2, wn2 = w & 3;
    int quad = lane >> 4, r16 = lane & 15;

    f32x4 acc[8][4];
#pragma unroll
    for (int i = 0; i < 8; ++i)
#pragma unroll
        for (int j = 0; j < 4; ++j) acc[i][j] = (f32x4){0.f, 0.f, 0.f, 0.f};

    const short* Ag0 = (const short*)A  + (size_t)(m0)       * K;
    const short* Ag1 = (const short*)A  + (size_t)(m0 + 128) * K;
    const short* Bg0 = (const short*)Bt + (size_t)(n0)       * K;
    const short* Bg1 = (const short*)Bt + (size_t)(n0 + 128) * K;

    // LDS map (shorts): A[p][h] @ (p*2+h)*8192 ; B[p][h] @ 32768+(p*2+h)*8192
    short* lds = smem;
    const short* Ard0 = lds + wm * 8192;                                   // p0, my m-half
    const short* Ard1 = lds + 16384 + wm * 8192;                           // p1
    const short* Brd0 = lds + 32768 + (wn2 >> 1) * 8192 + (wn2 & 1) * 4096; // p0, my 64 n-rows
    const short* Brd1 = lds + 49152 + (wn2 >> 1) * 8192 + (wn2 & 1) * 4096; // p1

    bf16x8 bfr[4];

#define STG(SRC, DSTOFF, KT)                                                   \
    { _Pragma("unroll")                                                        \
      for (int q_ = 0; q_ < 2; ++q_) {                                         \
          int s_ = q_ * 512 + tid;                                             \
          int row_ = s_ >> 3, cg_ = (s_ & 7) ^ (row_ & 7);                     \
          gload_lds16(SRC + (size_t)row_ * K + (KT) * 64 + cg_ * 8,            \
                      lds + (DSTOFF) + s_ * 8);                                \
      } }

#define PHASE(ARD, BRD, KS, IH, STAGE_CODE, WAIT_CODE)                         \
    {                                                                          \
        int kc_ = ((quad + (KS) * 4) ^ (r16 & 7)) * 8;                         \
        bf16x8 af0 = *(const bf16x8*)&(ARD)[(((IH)*4+0)*16 + r16) * 64 + kc_]; \
        bf16x8 af1 = *(const bf16x8*)&(ARD)[(((IH)*4+1)*16 + r16) * 64 + kc_]; \
        bf16x8 af2 = *(const bf16x8*)&(ARD)[(((IH)*4+2)*16 + r16) * 64 + kc_]; \
        bf16x8 af3 = *(const bf16x8*)&(ARD)[(((IH)*4+3)*16 + r16) * 64 + kc_]; \
        if ((IH) == 0) {                                                       \
            bfr[0] = *(const bf16x8*)&(BRD)[(0*16 + r16) * 64 + kc_];          \
            bfr[1] = *(const bf16x8*)&(BRD)[(1*16 + r16) * 64 + kc_];          \
            bfr[2] = *(const bf16x8*)&(BRD)[(2*16 + r16) * 64 + kc_];          \
            bfr[3] = *(const bf16x8*)&(BRD)[(3*16 + r16) * 64 + kc_];          \
        }                                                                      \
        STAGE_CODE;                                                            \
        asm volatile("s_barrier" ::: "memory");                                \
        __builtin_amdgcn_s_setprio(1);                                         \
        _Pragma("unroll")                                                      \
        for (int j_ = 0; j_ < 4; ++j_) {                                       \
            acc[(IH)*4+0][j_] = __builtin_amdgcn_mfma_f32_16x16x32_bf16(af0, bfr[j_], acc[(IH)*4+0][j_], 0, 0, 0); \
            acc[(IH)*4+1][j_] = __builtin_amdgcn_mfma_f32_16x16x32_bf16(af1, bfr[j_], acc[(IH)*4+1][j_], 0, 0, 0); \
            acc[(IH)*4+2][j_] = __builtin_amdgcn_mfma_f32_16x16x32_bf16(af2, bfr[j_], acc[(IH)*4+2][j_], 0, 0, 0); \
            acc[(IH)*4+3][j_] = __builtin_amdgcn_mfma_f32_16x16x32_bf16(af3, bfr[j_], acc[(IH)*4+3][j_], 0, 0, 0); \
        }                                                                      \
        __builtin_amdgcn_s_setprio(0);                                         \
        WAIT_CODE;                                                             \
        asm volatile("s_barrier" ::: "memory");                                \
    }

#define VM2 asm volatile("s_waitcnt vmcnt(2)" ::: "memory")
#define VM0 asm volatile("s_waitcnt vmcnt(0)" ::: "memory")
#define NOPX ((void)0)

    // Prologue: stage tile0 -> p0 (4 halves) + B[p1,h0](tile1); retire p0.
    STG(Ag0, 0,     0)
    STG(Ag1, 8192,  0)
    STG(Bg0, 32768, 0)
    STG(Bg1, 40960, 0)
    STG(Bg0, 49152, 1)
    VM2;
    asm volatile("s_barrier" ::: "memory");

    for (int u = 0; u < 15; ++u) {
        int t1 = 2 * u + 1, t2 = 2 * u + 2, t3 = 2 * u + 3;
        PHASE(Ard0, Brd0, 0, 0, STG(Ag0, 16384, t1), NOPX)   // P1
        PHASE(Ard0, Brd0, 0, 1, STG(Ag1, 24576, t1), NOPX)   // P2
        PHASE(Ard0, Brd0, 1, 0, STG(Bg1, 57344, t1), NOPX)   // P3
        PHASE(Ard0, Brd0, 1, 1, STG(Bg0, 32768, t2), VM2)    // P4
        PHASE(Ard1, Brd1, 0, 0, STG(Bg1, 40960, t2), NOPX)   // P5
        PHASE(Ard1, Brd1, 0, 1, STG(Ag0, 0,     t2), NOPX)   // P6
        PHASE(Ard1, Brd1, 1, 0, STG(Ag1, 8192,  t2), NOPX)   // P7
        PHASE(Ard1, Brd1, 1, 1, STG(Bg0, 49152, t3), VM2)    // P8
    }
    // Tail u=15: tiles 30 (p0) / 31 (p1); only tile-31 stages remain.
    PHASE(Ard0, Brd0, 0, 0, STG(Ag0, 16384, 31), NOPX)
    PHASE(Ard0, Brd0, 0, 1, STG(Ag1, 24576, 31), NOPX)
    PHASE(Ard0, Brd0, 1, 0, STG(Bg1, 57344, 31), NOPX)
    PHASE(Ard0, Brd0, 1, 1, NOPX, VM0)
    PHASE(Ard1, Brd1, 0, 0, NOPX, NOPX)
    PHASE(Ard1, Brd1, 0, 1, NOPX, NOPX)
    PHASE(Ard1, Brd1, 1, 0, NOPX, NOPX)
    PHASE(Ard1, Brd1, 1, 1, NOPX, NOPX)

#undef PHASE
#undef STG
#undef VM2
#undef VM0
#undef NOPX

    // ---- fused LSTM epilogue (R0-proven mapping; j = gate) ------------------
    // u = nb*64 + (wn2>>1)*32 + (wn2&1)*16 + r16 ; m = m0 + wm*128 + i*16 + quad*4 + rr
    int uo = nb * 64 + (wn2 >> 1) * 32 + (wn2 & 1) * 16 + r16;
    float bfv = b_f[uo], biv = b_i[uo], bcv = b_c[uo], bov = b_o[uo];
    float* out_h = out;
    float* out_c = out + (size_t)BATCH * UNITS;
#pragma unroll
    for (int i = 0; i < 8; ++i) {
#pragma unroll
        for (int rr = 0; rr < 4; ++rr) {
            int m = m0 + wm * 128 + i * 16 + quad * 4 + rr;
            float fg = sigm(acc[i][0][rr] + bfv);
            float ig = sigm(acc[i][1][rr] + biv);
            float cc = tanh_fast(acc[i][2][rr] + bcv);
            float og = sigm(acc[i][3][rr] + bov);
            float cold = cell[(size_t)m * UNITS + uo];
            float cn = fg * cold + ig * cc;
            out_h[(size_t)m * UNITS + uo] = og * tanh_fast(cn);
            out_c[(size_t)m * UNITS + uo] = cn;
        }
    }
}

extern "C" void kernel_launch(void* const* d_in, const int* in_sizes, int n_in,
                              void* d_out, int out_size, void* d_ws, size_t ws_size,
                              hipStream_t stream) {
    const float* inputs = (const float*)d_in[0];
    const float* hidden = (const float*)d_in[1];
    const float* cell   = (const float*)d_in[2];
    const float* Wf = (const float*)d_in[3];
    const float* bf_ = (const float*)d_in[4];
    const float* Wi = (const float*)d_in[5];
    const float* bi_ = (const float*)d_in[6];
    const float* Wc = (const float*)d_in[7];
    const float* bc_ = (const float*)d_in[8];
    const float* Wo = (const float*)d_in[9];
    const float* bo_ = (const float*)d_in[10];
    float* out = (float*)d_out;

    char* ws = (char*)d_ws;
    __hip_bfloat16* x  = (__hip_bfloat16*)ws;                  // 16 MB
    __hip_bfloat16* Wt = (__hip_bfloat16*)(ws + (16u << 20));  // 16 MB

    static bool attr_set = false;
    if (!attr_set) {
        hipFuncSetAttribute(reinterpret_cast<const void*>(gemm_lstm),
                            hipFuncAttributeMaxDynamicSharedMemorySize, 131072);
        attr_set = true;
    }

    prep<<<dim3(6144), dim3(256), 0, stream>>>(hidden, inputs, Wf, Wi, Wc, Wo, x, Wt);
    gemm_lstm<<<dim3(256), dim3(512), 131072, stream>>>(
        x, Wt, bf_, bi_, bc_, bo_, cell, out);
}